// Round 10
// baseline (2124.991 us; speedup 1.0000x reference)
//
#include <hip/hip_runtime.h>

#define B 512
#define L 1024
#define T 128
#define NROWS (L - 1)   /* 1023 */
#define SEG 64
#define NSEG 16

typedef unsigned char u8;
typedef float f2 __attribute__((ext_vector_type(2)));

#define M3(a, b, c) fmaxf(fmaxf((a), (b)), (c))

// Packed fp32 add (VOP3P). Elementwise IEEE f32 add — bitwise identical to
// two v_add_f32 (proven bitwise in R5-R8).
static __device__ __forceinline__ f2 pkadd(f2 a, f2 b) {
    f2 d;
    asm("v_pk_add_f32 %0, %1, %2" : "=v"(d) : "v"(a), "v"(b));
    return d;
}
// 3-input max (VOP3). Pure selection — bitwise-safe for finite values.
static __device__ __forceinline__ float mx3(float a, float b, float c) {
    float d;
    asm("v_max3_f32 %0, %1, %2, %3" : "=v"(d) : "v"(a), "v"(b), "v"(c));
    return d;
}

// barrier WITHOUT vmcnt(0) drain (used by fallback kernels only).
#define BAR()                                                  \
    do {                                                       \
        asm volatile("s_waitcnt lgkmcnt(0)" ::: "memory");     \
        __builtin_amdgcn_s_barrier();                          \
        asm volatile("" ::: "memory");                         \
    } while (0)

// Intra-wave LDS write->read fence (single-wave kernel: no s_barrier needed).
#define LDSFENCE() asm volatile("s_waitcnt lgkmcnt(0)" ::: "memory")

// ===========================================================================
// FAST PATH (needs ~268 MB workspace)
// ===========================================================================

// ---------------------------------------------------------------------------
// Forward, VALUES ONLY. ONE WAVE per batch; thread j owns columns j and j+64.
// trans columns in 256 VGPRs (static indexing). Per step: publish 2 floats to
// LDS, lgkmcnt(0), 32 broadcast ds_read_b128 (reused by both columns -> DS
// insts halved vs R6), 128 pkadd + 128 max3. NO barriers (single wave).
// Exact: s = (prev[i] + obs[j]) + trans[i][j]; max = selection (order-free).
// ---------------------------------------------------------------------------
__global__ __launch_bounds__(64, 1) void viterbi_fwd_val(
    const float* __restrict__ emit, const float* __restrict__ trans,
    const float* __restrict__ w, float* __restrict__ out,
    float* __restrict__ prevws, int* __restrict__ lastTag)
{
    const int b = blockIdx.x;
    const int j = threadIdx.x;           // owns columns j and j+64

    __shared__ __align__(16) float pb[T];   // one prev row (single wave)

    // trans columns j and j+64 -> 128 f2 (256 VGPRs), k-pairs for pkadd
    f2 trp0[64], trp1[64];
#pragma unroll
    for (int g = 0; g < 64; ++g) {
        f2 a, c;
        a.x = trans[(size_t)(2 * g) * T + j];
        a.y = trans[(size_t)(2 * g + 1) * T + j];
        c.x = trans[(size_t)(2 * g) * T + j + 64];
        c.y = trans[(size_t)(2 * g + 1) * T + j + 64];
        trp0[g] = a; trp1[g] = c;
    }

    const float w0 = w[j], w1 = w[j + 64];
    const size_t eb = (size_t)b * L * T;
    float* prow = prevws + (size_t)b * NROWS * T;

    // t = 0
    float bv0 = emit[eb + j] * w0;
    float bv1 = emit[eb + j + 64] * w1;
    prow[j] = bv0; prow[j + 64] = bv1;          // row 0

    // emit prefetch depth 2 (vmcnt never drained -> spans steps freely)
    float rc0 = emit[eb + (size_t)T + j],     rc1 = emit[eb + (size_t)T + j + 64];
    float r10 = emit[eb + (size_t)2 * T + j], r11 = emit[eb + (size_t)2 * T + j + 64];

#define STEP_BODY(T_, STORE_)                                                  \
    {                                                                          \
        const int t_ = (T_);                                                   \
        pb[j] = bv0; pb[j + 64] = bv1;          /* publish prev row */         \
        const int tn_ = (t_ + 2 < L) ? (t_ + 2) : (L - 1);                     \
        const float r20 = emit[eb + (size_t)tn_ * T + j];                      \
        const float r21 = emit[eb + (size_t)tn_ * T + j + 64];                 \
        const float obs0 = rc0 * w0, obs1 = rc1 * w1;                          \
        f2 od0; od0.x = obs0; od0.y = obs0;                                    \
        f2 od1; od1.x = obs1; od1.y = obs1;                                    \
        float a0 = -3.4e38f, a1 = -3.4e38f, a2 = -3.4e38f, a3 = -3.4e38f;      \
        LDSFENCE();                             /* writes before reads */      \
        _Pragma("unroll")                                                      \
        for (int g = 0; g < 32; ++g) {                                         \
            const float4 p = *(const float4*)&pb[4 * g];   /* broadcast */     \
            f2 plo; plo.x = p.x; plo.y = p.y;                                  \
            f2 phi; phi.x = p.z; phi.y = p.w;                                  \
            const f2 sA0 = pkadd(pkadd(plo, od0), trp0[2 * g]);                \
            const f2 sA1 = pkadd(pkadd(phi, od0), trp0[2 * g + 1]);            \
            const f2 sB0 = pkadd(pkadd(plo, od1), trp1[2 * g]);                \
            const f2 sB1 = pkadd(pkadd(phi, od1), trp1[2 * g + 1]);            \
            a0 = mx3(a0, sA0.x, sA0.y);                                        \
            a1 = mx3(a1, sA1.x, sA1.y);                                        \
            a2 = mx3(a2, sB0.x, sB0.y);                                        \
            a3 = mx3(a3, sB1.x, sB1.y);                                        \
        }                                                                      \
        const float nb0 = fmaxf(a0, a1);                                       \
        const float nb1 = fmaxf(a2, a3);                                       \
        if (STORE_) {                                                          \
            prow[(size_t)t_ * T + j] = nb0;                                    \
            prow[(size_t)t_ * T + j + 64] = nb1;                               \
        }                                                                      \
        bv0 = nb0; bv1 = nb1;                                                  \
        rc0 = r10; r10 = r20;                                                  \
        rc1 = r11; r11 = r21;                                                  \
    }

#pragma unroll 1
    for (int t = 1; t < L - 1; ++t) STEP_BODY(t, true)
    STEP_BODY(L - 1, false)
#undef STEP_BODY

    // final reduce: best_score + first-occurrence argmax over 128 columns.
    float rv; int rj;
    if (bv1 > bv0) { rv = bv1; rj = j + 64; } else { rv = bv0; rj = j; }
#pragma unroll
    for (int m = 1; m <= 32; m <<= 1) {
        const float pv = __shfl_xor(rv, m);
        const int   pj = __shfl_xor(rj, m);
        if (pv > rv || (pv == rv && pj < rj)) { rv = pv; rj = pj; }
    }
    if (j == 0) {
        out[(size_t)B * L + b] = rv;
        out[(size_t)b * L + (L - 1)] = (float)rj;
        lastTag[b] = rj;
    }
}

// ---------------------------------------------------------------------------
// Backtrace v2 (R5 body, proven; ctz made benign on equality miss).
// ---------------------------------------------------------------------------
__global__ __launch_bounds__(64, 1) void backtrace(
    const float* __restrict__ emit, const float* __restrict__ trans,
    const float* __restrict__ w, const float* __restrict__ prevws,
    const int* __restrict__ lastTag, float* __restrict__ out)
{
    const int b = blockIdx.x;
    const int lane = threadIdx.x;
    __shared__ float transT[T * T];   // 64 KB

    // stage transposed + swizzled: transT[j][i ^ (j&31)] = trans[i][j]
#pragma unroll 4
    for (int it = 0; it < (T * T) / 64; ++it) {
        const int k = it * 64 + lane;
        const int i = k >> 7, jj = k & 127;
        transT[jj * T + (i ^ (jj & 31))] = trans[k];
    }

    const float w0 = w[lane], w1 = w[lane + 64];
    const size_t pbase = (size_t)b * NROWS * T;
    const size_t ebase = (size_t)b * L * T;
    const size_t obase = (size_t)b * L;

    float rp0[8], rp1[8], re0[8], re1[8];
#pragma unroll
    for (int k = 0; k < 8; ++k) {
        rp0[k] = prevws[pbase + (size_t)(1022 - k) * T + lane];
        rp1[k] = prevws[pbase + (size_t)(1022 - k) * T + lane + 64];
        re0[k] = emit[ebase + (size_t)(1023 - k) * T + lane];
        re1[k] = emit[ebase + (size_t)(1023 - k) * T + lane + 64];
    }

    int idx = lastTag[b];
    const float bsc = out[(size_t)B * L + b];
    float pp0 = bsc, pp1 = bsc;
    __syncthreads();

    int r = 1022;

#define BODY(U_)                                                               \
    {                                                                          \
        const float c0_ = rp0[U_], c1_ = rp1[U_];                              \
        const float e0_ = re0[U_], e1_ = re1[U_];                              \
        const int pr = (r >= 8) ? (r - 8) : 0;                                 \
        rp0[U_] = prevws[pbase + (size_t)pr * T + lane];                       \
        rp1[U_] = prevws[pbase + (size_t)pr * T + lane + 64];                  \
        re0[U_] = emit[ebase + (size_t)(pr + 1) * T + lane];                   \
        re1[U_] = emit[ebase + (size_t)(pr + 1) * T + lane + 64];              \
        const int sl = idx & 63;                                               \
        const bool lo = idx < 64;                                              \
        const float bv  = __shfl(lo ? pp0 : pp1, sl);                          \
        const float ew0 = e0_ * w0, ew1 = e1_ * w1;                            \
        const float obs = __shfl(lo ? ew0 : ew1, sl);                          \
        const int xc = lane ^ (idx & 31);                                      \
        const float t0 = transT[idx * T + xc];                                 \
        const float t1 = transT[idx * T + 64 + xc];                            \
        const float s0 = (c0_ + obs) + t0;                                     \
        const float s1 = (c1_ + obs) + t1;                                     \
        const unsigned long long m0 = __ballot(s0 == bv);                      \
        const unsigned long long m1 = __ballot(s1 == bv);                      \
        idx = (m0 != 0ULL) ? __builtin_ctzll(m0)                               \
            : ((m1 != 0ULL) ? 64 + __builtin_ctzll(m1) : idx);                 \
        if (lane == 0) out[obase + r] = (float)idx;                            \
        pp0 = c0_; pp1 = c1_;                                                  \
        --r;                                                                   \
    }

#pragma unroll 1
    for (int g = 0; g < 127; ++g) {    // 127 x 8 = 1016 iters: r = 1022 .. 7
        BODY(0) BODY(1) BODY(2) BODY(3) BODY(4) BODY(5) BODY(6) BODY(7)
    }
    BODY(0) BODY(1) BODY(2) BODY(3) BODY(4) BODY(5) BODY(6)
#undef BODY
}

// ===========================================================================
// FALLBACK PATH (R3 kernels, used when ws_size < 268 MB)
// ===========================================================================
__global__ __launch_bounds__(512, 4) void viterbi_fwd_slow(
    const float* __restrict__ emit, const float* __restrict__ trans,
    const float* __restrict__ w, float* __restrict__ out,
    u8* __restrict__ bps, int* __restrict__ lastTag)
{
    const int b   = blockIdx.x;
    const int tid = threadIdx.x;
    const int h   = tid & 3;
    const int j   = tid >> 2;
    const int hbase = h << 5;
    const bool lane0 = (h == 0);
    const int INF = 0x7fffffff;

    __shared__ __align__(16) float prevbuf[2 * T];
    __shared__ float swv[8];
    __shared__ int   swj[8];

    f2 tc2[16];
#pragma unroll
    for (int q = 0; q < 8; ++q) {
        f2 a, c;
        a.x = trans[(size_t)(hbase + 4 * q + 0) * T + j];
        a.y = trans[(size_t)(hbase + 4 * q + 1) * T + j];
        c.x = trans[(size_t)(hbase + 4 * q + 2) * T + j];
        c.y = trans[(size_t)(hbase + 4 * q + 3) * T + j];
        tc2[2 * q] = a; tc2[2 * q + 1] = c;
    }

    const float wj = w[j];
    const size_t ebase = (size_t)b * L * T;
    u8* bprow = bps + (size_t)b * NROWS * T;

    const char* prd = (const char*)prevbuf + 128 * h;
    char* pwr = (char*)prevbuf + 16 * ((j >> 2) ^ (j >> 5)) + 4 * (j & 3);

    const float e0 = emit[ebase + j] * wj;
    if (lane0) *(float*)pwr = e0;
    float myprev = e0;
    float raw_cur = emit[ebase + (size_t)T + j];
    int bidx_prev = 0;
    __syncthreads();

#define STEP(T_, ROFF_, WOFF_)                                                 \
    {                                                                          \
        const int t_ = (T_);                                                   \
        if (lane0 && t_ >= 2)                                                  \
            bprow[(size_t)(t_ - 2) * T + j] = (u8)bidx_prev;                   \
        const int tn_ = (t_ + 1 < L) ? (t_ + 1) : (L - 1);                     \
        const float raw_next_ = emit[ebase + (size_t)tn_ * T + j];             \
        const float obs_ = raw_cur * wj;                                       \
        f2 od_; od_.x = obs_; od_.y = obs_;                                    \
        f2 sv[16];                                                             \
        _Pragma("unroll")                                                      \
        for (int q = 0; q < 8; ++q) {                                          \
            const float4 p = *(const float4*)(prd + (ROFF_) + 16 * (q ^ h));   \
            f2 plo; plo.x = p.x; plo.y = p.y;                                  \
            f2 phi; phi.x = p.z; phi.y = p.w;                                  \
            sv[2 * q]     = (plo + od_) + tc2[2 * q];                          \
            sv[2 * q + 1] = (phi + od_) + tc2[2 * q + 1];                      \
        }                                                                      \
        float cm[4]; int loc[4];                                               \
        _Pragma("unroll")                                                      \
        for (int c = 0; c < 4; ++c) {                                          \
            const float s0 = sv[4 * c + 0].x, s1 = sv[4 * c + 0].y;            \
            const float s2 = sv[4 * c + 1].x, s3 = sv[4 * c + 1].y;            \
            const float s4 = sv[4 * c + 2].x, s5 = sv[4 * c + 2].y;            \
            const float s6 = sv[4 * c + 3].x, s7 = sv[4 * c + 3].y;            \
            const float m = M3(M3(s0, s1, s2), M3(s3, s4, s5),                 \
                               fmaxf(s6, s7));                                 \
            int k = 0;                                                         \
            k = (s7 == m) ? 7 : k; k = (s6 == m) ? 6 : k;                      \
            k = (s5 == m) ? 5 : k; k = (s4 == m) ? 4 : k;                      \
            k = (s3 == m) ? 3 : k; k = (s2 == m) ? 2 : k;                      \
            k = (s1 == m) ? 1 : k;                                             \
            cm[c] = m; loc[c] = 8 * c + k;                                     \
        }                                                                      \
        float bv = fmaxf(fmaxf(cm[0], cm[1]), fmaxf(cm[2], cm[3]));            \
        const int l0 = (cm[0] == bv) ? loc[0] : INF;                           \
        const int l1 = (cm[1] == bv) ? loc[1] : INF;                           \
        const int l2 = (cm[2] == bv) ? loc[2] : INF;                           \
        const int l3 = (cm[3] == bv) ? loc[3] : INF;                           \
        const int lm = min(min(min(l0, l1), l2), l3);                          \
        int gi = hbase + lm;                                                   \
        const float lv = bv;                                                   \
        bv = fmaxf(bv, __shfl_xor(bv, 1));                                     \
        bv = fmaxf(bv, __shfl_xor(bv, 2));                                     \
        int ii = (lv == bv) ? gi : INF;                                        \
        ii = min(ii, __shfl_xor(ii, 1));                                       \
        ii = min(ii, __shfl_xor(ii, 2));                                       \
        if (lane0) *(float*)(pwr + (WOFF_)) = bv;                              \
        myprev = bv;                                                           \
        bidx_prev = ii;                                                        \
        raw_cur = raw_next_;                                                   \
        __syncthreads();                                                       \
    }

    int t = 1;
    while (t + 1 < L) {
        STEP(t, 0, 512)
        STEP(t + 1, 512, 0)
        t += 2;
    }
    STEP(1023, 0, 512)
#undef STEP

    if (lane0) bprow[(size_t)(NROWS - 1) * T + j] = (u8)bidx_prev;

    float rv = myprev; int rj = j;
#pragma unroll
    for (int m = 4; m <= 32; m <<= 1) {
        const float pv = __shfl_xor(rv, m);
        const int   pj = __shfl_xor(rj, m);
        if (pv > rv || (pv == rv && pj < rj)) { rv = pv; rj = pj; }
    }
    if ((tid & 63) == 0) { swv[tid >> 6] = rv; swj[tid >> 6] = rj; }
    __syncthreads();
    if (tid == 0) {
        float fv = swv[0]; int fj = swj[0];
#pragma unroll
        for (int wv = 1; wv < 8; ++wv) {
            if (swv[wv] > fv || (swv[wv] == fv && swj[wv] < fj)) {
                fv = swv[wv]; fj = swj[wv];
            }
        }
        out[(size_t)B * L + b] = fv;
        out[(size_t)b * L + (L - 1)] = (float)fj;
        lastTag[b] = fj;
    }
}

__global__ __launch_bounds__(T) void segcomp(const u8* __restrict__ bps,
                                             u8* __restrict__ comp)
{
    const int s = blockIdx.x & (NSEG - 1);
    const int b = blockIdx.x >> 4;
    const int r0 = s * SEG;
    const int cnt = (NROWS - r0 < SEG) ? (NROWS - r0) : SEG;

    __shared__ __align__(16) u8 rows[SEG * T];
    const uint4* src = (const uint4*)(bps + ((size_t)b * NROWS + r0) * T);
    uint4* dst = (uint4*)rows;
    const int nvec = cnt * (T / 16);
    for (int k = threadIdx.x; k < nvec; k += T) dst[k] = src[k];
    __syncthreads();

    int x = threadIdx.x;
    for (int k = cnt - 1; k >= 0; --k) x = rows[k * T + x];
    comp[((size_t)b * NSEG + s) * T + threadIdx.x] = (u8)x;
}

__global__ void chainseg(const u8* __restrict__ comp,
                         const int* __restrict__ lastTag,
                         float* __restrict__ out)
{
    const int b = blockIdx.x * blockDim.x + threadIdx.x;
    if (b >= B) return;
    int e = lastTag[b];
#pragma unroll 1
    for (int s = NSEG - 1; s >= 0; --s) {
        e = comp[((size_t)b * NSEG + s) * T + e];
        out[(size_t)b * L + s * SEG] = (float)e;
    }
}

__global__ __launch_bounds__(T) void fillseg(const u8* __restrict__ bps,
                                             const int* __restrict__ lastTag,
                                             float* __restrict__ out)
{
    const int s = blockIdx.x & (NSEG - 1);
    const int b = blockIdx.x >> 4;
    const int r0 = s * SEG;
    const int cnt = (NROWS - r0 < SEG) ? (NROWS - r0) : SEG;

    __shared__ __align__(16) u8 rows[SEG * T];
    const uint4* src = (const uint4*)(bps + ((size_t)b * NROWS + r0) * T);
    uint4* dst = (uint4*)rows;
    const int nvec = cnt * (T / 16);
    for (int k = threadIdx.x; k < nvec; k += T) dst[k] = src[k];
    __syncthreads();

    if (threadIdx.x == 0) {
        int e = (s == NSEG - 1) ? lastTag[b]
                                : (int)out[(size_t)b * L + (size_t)(s + 1) * SEG];
        for (int k = cnt - 1; k >= 1; --k) {
            e = rows[k * T + e];
            out[(size_t)b * L + r0 + k] = (float)e;
        }
    }
}

// ---------------------------------------------------------------------------
extern "C" void kernel_launch(void* const* d_in, const int* in_sizes, int n_in,
                              void* d_out, int out_size, void* d_ws, size_t ws_size,
                              hipStream_t stream)
{
    const float* emit  = (const float*)d_in[0];
    const float* trans = (const float*)d_in[1];
    const float* w     = (const float*)d_in[2];
    float* out = (float*)d_out;

    const size_t prev_bytes = (size_t)B * NROWS * T * sizeof(float); // 268 MB
    const size_t need_fast  = prev_bytes + B * sizeof(int);

    if (ws_size >= need_fast) {
        float* prevws  = (float*)d_ws;
        int*   lastTag = (int*)((char*)d_ws + prev_bytes);
        viterbi_fwd_val<<<B, 64, 0, stream>>>(emit, trans, w, out, prevws, lastTag);
        backtrace<<<B, 64, 0, stream>>>(emit, trans, w, prevws, lastTag, out);
    } else {
        u8*  bps     = (u8*)d_ws;
        u8*  comp    = bps + (size_t)B * NROWS * T;
        int* lastTag = (int*)(comp + (size_t)B * NSEG * T);
        viterbi_fwd_slow<<<B, 512, 0, stream>>>(emit, trans, w, out, bps, lastTag);
        segcomp<<<B * NSEG, T, 0, stream>>>(bps, comp);
        chainseg<<<2, 256, 0, stream>>>(comp, lastTag, out);
        fillseg<<<B * NSEG, T, 0, stream>>>(bps, lastTag, out);
    }
}

// Round 11
// 867.403 us; speedup vs baseline: 2.4498x; 2.4498x over previous
//
#include <hip/hip_runtime.h>

#define B 512
#define L 1024
#define T 128
#define NROWS (L - 1)   /* 1023 */
#define SEG 64
#define NSEG 16

typedef unsigned char u8;
typedef float f2 __attribute__((ext_vector_type(2)));

#define M3(a, b, c) fmaxf(fmaxf((a), (b)), (c))

// Packed fp32 add (VOP3P). Elementwise IEEE f32 add — bitwise identical to
// two v_add_f32.
static __device__ __forceinline__ f2 pkadd(f2 a, f2 b) {
    f2 d;
    asm("v_pk_add_f32 %0, %1, %2" : "=v"(d) : "v"(a), "v"(b));
    return d;
}
// 3-input max (VOP3). Pure selection — bitwise-safe for finite values.
static __device__ __forceinline__ float mx3(float a, float b, float c) {
    float d;
    asm("v_max3_f32 %0, %1, %2, %3" : "=v"(d) : "v"(a), "v"(b), "v"(c));
    return d;
}

// barrier WITHOUT vmcnt(0) drain: LDS visibility only (m201-verified pattern).
#define BAR()                                                  \
    do {                                                       \
        asm volatile("s_waitcnt lgkmcnt(0)" ::: "memory");     \
        __builtin_amdgcn_s_barrier();                          \
        asm volatile("" ::: "memory");                         \
    } while (0)

// ===========================================================================
// FAST PATH (needs ~268 MB workspace)
// ===========================================================================

// ---------------------------------------------------------------------------
// Forward, VALUES ONLY — the R6-measured optimum (735 µs, absmax 0).
// 512 thr: h = tid&3 owns 32 i's, j = tid>>2. v_pk_add_f32 + v_max3_f32 tree.
// Exact: s = (prev[i] + obs[j]) + trans[i][j]; max = selection (order-free).
// prevbuf XOR-swizzled by 16B granule (phys g = g ^ (g>>3)) -> conflict-free.
// DS-pipe floor note: all-to-all via LDS b128 costs an invariant 64
// DS-insts/batch-step; measured wall is ~89% of that floor (R5-R10 ladder).
// ---------------------------------------------------------------------------
__global__ __launch_bounds__(512, 4) void viterbi_fwd_val(
    const float* __restrict__ emit, const float* __restrict__ trans,
    const float* __restrict__ w, float* __restrict__ out,
    float* __restrict__ prevws, int* __restrict__ lastTag)
{
    const int b   = blockIdx.x;
    const int tid = threadIdx.x;
    const int h   = tid & 3;
    const int j   = tid >> 2;
    const int hbase = h << 5;
    const bool lane0 = (h == 0);

    __shared__ __align__(16) float prevbuf[2 * T];
    __shared__ float swv[8];
    __shared__ int   swj[8];

    f2 tc2[16];
#pragma unroll
    for (int q = 0; q < 8; ++q) {
        f2 a, c;
        a.x = trans[(size_t)(hbase + 4 * q + 0) * T + j];
        a.y = trans[(size_t)(hbase + 4 * q + 1) * T + j];
        c.x = trans[(size_t)(hbase + 4 * q + 2) * T + j];
        c.y = trans[(size_t)(hbase + 4 * q + 3) * T + j];
        tc2[2 * q] = a; tc2[2 * q + 1] = c;
    }

    const float wj = w[j];
    const size_t ebase = (size_t)b * L * T;
    float* prow = prevws + (size_t)b * NROWS * T;

    const char* prd = (const char*)prevbuf + 128 * h;
    char* pwr = (char*)prevbuf + 16 * ((j >> 2) ^ (j >> 5)) + 4 * (j & 3);

    const float e0 = emit[ebase + j] * wj;
    if (lane0) *(float*)pwr = e0;
    if (h == 1) prow[j] = e0;                       // prev row 0
    float myprev = e0;
    float r_c = emit[ebase + (size_t)T + j];        // row 1
    float r_1 = emit[ebase + (size_t)2 * T + j];    // row 2
    float bv_prev = 0.0f;
    BAR();

#define SVX(K_) ((K_ & 1) ? sv[(K_) >> 1].y : sv[(K_) >> 1].x)
#define STEP(T_, ROFF_, WOFF_)                                                 \
    {                                                                          \
        const int t_ = (T_);                                                   \
        if (h == 1 && t_ >= 2)                                                 \
            prow[(size_t)(t_ - 1) * T + j] = bv_prev;                          \
        const int tn_ = (t_ + 2 < L) ? (t_ + 2) : (L - 1);                     \
        const float r_2 = emit[ebase + (size_t)tn_ * T + j];                   \
        const float obs_ = r_c * wj;                                           \
        f2 od_; od_.x = obs_; od_.y = obs_;                                    \
        f2 sv[16];                                                             \
        _Pragma("unroll")                                                      \
        for (int q = 0; q < 8; ++q) {                                          \
            const float4 p = *(const float4*)(prd + (ROFF_) + 16 * (q ^ h));   \
            f2 plo; plo.x = p.x; plo.y = p.y;                                  \
            f2 phi; phi.x = p.z; phi.y = p.w;                                  \
            sv[2 * q]     = pkadd(pkadd(plo, od_), tc2[2 * q]);                \
            sv[2 * q + 1] = pkadd(pkadd(phi, od_), tc2[2 * q + 1]);            \
        }                                                                      \
        const float m0 = mx3(SVX(0),  SVX(1),  SVX(2));                        \
        const float m1 = mx3(SVX(3),  SVX(4),  SVX(5));                        \
        const float m2 = mx3(SVX(6),  SVX(7),  SVX(8));                        \
        const float m3 = mx3(SVX(9),  SVX(10), SVX(11));                       \
        const float m4 = mx3(SVX(12), SVX(13), SVX(14));                       \
        const float m5 = mx3(SVX(15), SVX(16), SVX(17));                       \
        const float m6 = mx3(SVX(18), SVX(19), SVX(20));                       \
        const float m7 = mx3(SVX(21), SVX(22), SVX(23));                       \
        const float m8 = mx3(SVX(24), SVX(25), SVX(26));                       \
        const float m9 = mx3(SVX(27), SVX(28), SVX(29));                       \
        const float m10 = fmaxf(SVX(30), SVX(31));                             \
        const float n0 = mx3(m0, m1, m2);                                      \
        const float n1 = mx3(m3, m4, m5);                                      \
        const float n2 = mx3(m6, m7, m8);                                      \
        const float n3 = fmaxf(m9, m10);                                       \
        float bv = fmaxf(mx3(n0, n1, n2), n3);                                 \
        bv = fmaxf(bv, __shfl_xor(bv, 1));                                     \
        bv = fmaxf(bv, __shfl_xor(bv, 2));                                     \
        if (lane0) *(float*)(pwr + (WOFF_)) = bv;                              \
        myprev = bv;                                                           \
        bv_prev = bv;                                                          \
        r_c = r_1; r_1 = r_2;                                                  \
        BAR();                                                                 \
    }

    int t = 1;
    while (t + 1 < L) {
        STEP(t, 0, 512)
        STEP(t + 1, 512, 0)
        t += 2;
    }
    STEP(1023, 0, 512)
#undef STEP
#undef SVX

    float rv = myprev; int rj = j;
#pragma unroll
    for (int m = 4; m <= 32; m <<= 1) {
        const float pv = __shfl_xor(rv, m);
        const int   pj = __shfl_xor(rj, m);
        if (pv > rv || (pv == rv && pj < rj)) { rv = pv; rj = pj; }
    }
    if ((tid & 63) == 0) { swv[tid >> 6] = rv; swj[tid >> 6] = rj; }
    __syncthreads();
    if (tid == 0) {
        float fv = swv[0]; int fj = swj[0];
#pragma unroll
        for (int wv = 1; wv < 8; ++wv) {
            if (swv[wv] > fv || (swv[wv] == fv && swj[wv] < fj)) {
                fv = swv[wv]; fj = swj[wv];
            }
        }
        out[(size_t)B * L + b] = fv;
        out[(size_t)b * L + (L - 1)] = (float)fj;
        lastTag[b] = fj;
    }
}

// ---------------------------------------------------------------------------
// Backtrace: ballot-rescan, 8-deep register ring (R5-proven ~117 µs),
// with benign ctz fallback (R10-proven): a miss keeps idx instead of UB.
// ---------------------------------------------------------------------------
__global__ __launch_bounds__(64, 1) void backtrace(
    const float* __restrict__ emit, const float* __restrict__ trans,
    const float* __restrict__ w, const float* __restrict__ prevws,
    const int* __restrict__ lastTag, float* __restrict__ out)
{
    const int b = blockIdx.x;
    const int lane = threadIdx.x;
    __shared__ float transT[T * T];   // 64 KB

    // stage transposed + swizzled: transT[j][i ^ (j&31)] = trans[i][j]
#pragma unroll 4
    for (int it = 0; it < (T * T) / 64; ++it) {
        const int k = it * 64 + lane;
        const int i = k >> 7, jj = k & 127;
        transT[jj * T + (i ^ (jj & 31))] = trans[k];
    }

    const float w0 = w[lane], w1 = w[lane + 64];
    const size_t pbase = (size_t)b * NROWS * T;
    const size_t ebase = (size_t)b * L * T;
    const size_t obase = (size_t)b * L;

    float rp0[8], rp1[8], re0[8], re1[8];
#pragma unroll
    for (int k = 0; k < 8; ++k) {
        rp0[k] = prevws[pbase + (size_t)(1022 - k) * T + lane];
        rp1[k] = prevws[pbase + (size_t)(1022 - k) * T + lane + 64];
        re0[k] = emit[ebase + (size_t)(1023 - k) * T + lane];
        re1[k] = emit[ebase + (size_t)(1023 - k) * T + lane + 64];
    }

    int idx = lastTag[b];
    const float bsc = out[(size_t)B * L + b];
    float pp0 = bsc, pp1 = bsc;
    __syncthreads();

    int r = 1022;

#define BODY(U_)                                                               \
    {                                                                          \
        const float c0_ = rp0[U_], c1_ = rp1[U_];                              \
        const float e0_ = re0[U_], e1_ = re1[U_];                              \
        const int pr = (r >= 8) ? (r - 8) : 0;                                 \
        rp0[U_] = prevws[pbase + (size_t)pr * T + lane];                       \
        rp1[U_] = prevws[pbase + (size_t)pr * T + lane + 64];                  \
        re0[U_] = emit[ebase + (size_t)(pr + 1) * T + lane];                   \
        re1[U_] = emit[ebase + (size_t)(pr + 1) * T + lane + 64];              \
        const int sl = idx & 63;                                               \
        const bool lo = idx < 64;                                              \
        const float bv  = __shfl(lo ? pp0 : pp1, sl);                          \
        const float ew0 = e0_ * w0, ew1 = e1_ * w1;                            \
        const float obs = __shfl(lo ? ew0 : ew1, sl);                          \
        const int xc = lane ^ (idx & 31);                                      \
        const float t0 = transT[idx * T + xc];                                 \
        const float t1 = transT[idx * T + 64 + xc];                            \
        const float s0 = (c0_ + obs) + t0;                                     \
        const float s1 = (c1_ + obs) + t1;                                     \
        const unsigned long long m0 = __ballot(s0 == bv);                      \
        const unsigned long long m1 = __ballot(s1 == bv);                      \
        idx = (m0 != 0ULL) ? __builtin_ctzll(m0)                               \
            : ((m1 != 0ULL) ? 64 + __builtin_ctzll(m1) : idx);                 \
        if (lane == 0) out[obase + r] = (float)idx;                            \
        pp0 = c0_; pp1 = c1_;                                                  \
        --r;                                                                   \
    }

#pragma unroll 1
    for (int g = 0; g < 127; ++g) {    // 127 x 8 = 1016 iters: r = 1022 .. 7
        BODY(0) BODY(1) BODY(2) BODY(3) BODY(4) BODY(5) BODY(6) BODY(7)
    }
    BODY(0) BODY(1) BODY(2) BODY(3) BODY(4) BODY(5) BODY(6)
#undef BODY
}

// ===========================================================================
// FALLBACK PATH (R3 kernels, used when ws_size < 268 MB)
// ===========================================================================
__global__ __launch_bounds__(512, 4) void viterbi_fwd_slow(
    const float* __restrict__ emit, const float* __restrict__ trans,
    const float* __restrict__ w, float* __restrict__ out,
    u8* __restrict__ bps, int* __restrict__ lastTag)
{
    const int b   = blockIdx.x;
    const int tid = threadIdx.x;
    const int h   = tid & 3;
    const int j   = tid >> 2;
    const int hbase = h << 5;
    const bool lane0 = (h == 0);
    const int INF = 0x7fffffff;

    __shared__ __align__(16) float prevbuf[2 * T];
    __shared__ float swv[8];
    __shared__ int   swj[8];

    f2 tc2[16];
#pragma unroll
    for (int q = 0; q < 8; ++q) {
        f2 a, c;
        a.x = trans[(size_t)(hbase + 4 * q + 0) * T + j];
        a.y = trans[(size_t)(hbase + 4 * q + 1) * T + j];
        c.x = trans[(size_t)(hbase + 4 * q + 2) * T + j];
        c.y = trans[(size_t)(hbase + 4 * q + 3) * T + j];
        tc2[2 * q] = a; tc2[2 * q + 1] = c;
    }

    const float wj = w[j];
    const size_t ebase = (size_t)b * L * T;
    u8* bprow = bps + (size_t)b * NROWS * T;

    const char* prd = (const char*)prevbuf + 128 * h;
    char* pwr = (char*)prevbuf + 16 * ((j >> 2) ^ (j >> 5)) + 4 * (j & 3);

    const float e0 = emit[ebase + j] * wj;
    if (lane0) *(float*)pwr = e0;
    float myprev = e0;
    float raw_cur = emit[ebase + (size_t)T + j];
    int bidx_prev = 0;
    __syncthreads();

#define STEP(T_, ROFF_, WOFF_)                                                 \
    {                                                                          \
        const int t_ = (T_);                                                   \
        if (lane0 && t_ >= 2)                                                  \
            bprow[(size_t)(t_ - 2) * T + j] = (u8)bidx_prev;                   \
        const int tn_ = (t_ + 1 < L) ? (t_ + 1) : (L - 1);                     \
        const float raw_next_ = emit[ebase + (size_t)tn_ * T + j];             \
        const float obs_ = raw_cur * wj;                                       \
        f2 od_; od_.x = obs_; od_.y = obs_;                                    \
        f2 sv[16];                                                             \
        _Pragma("unroll")                                                      \
        for (int q = 0; q < 8; ++q) {                                          \
            const float4 p = *(const float4*)(prd + (ROFF_) + 16 * (q ^ h));   \
            f2 plo; plo.x = p.x; plo.y = p.y;                                  \
            f2 phi; phi.x = p.z; phi.y = p.w;                                  \
            sv[2 * q]     = (plo + od_) + tc2[2 * q];                          \
            sv[2 * q + 1] = (phi + od_) + tc2[2 * q + 1];                      \
        }                                                                      \
        float cm[4]; int loc[4];                                               \
        _Pragma("unroll")                                                      \
        for (int c = 0; c < 4; ++c) {                                          \
            const float s0 = sv[4 * c + 0].x, s1 = sv[4 * c + 0].y;            \
            const float s2 = sv[4 * c + 1].x, s3 = sv[4 * c + 1].y;            \
            const float s4 = sv[4 * c + 2].x, s5 = sv[4 * c + 2].y;            \
            const float s6 = sv[4 * c + 3].x, s7 = sv[4 * c + 3].y;            \
            const float m = M3(M3(s0, s1, s2), M3(s3, s4, s5),                 \
                               fmaxf(s6, s7));                                 \
            int k = 0;                                                         \
            k = (s7 == m) ? 7 : k; k = (s6 == m) ? 6 : k;                      \
            k = (s5 == m) ? 5 : k; k = (s4 == m) ? 4 : k;                      \
            k = (s3 == m) ? 3 : k; k = (s2 == m) ? 2 : k;                      \
            k = (s1 == m) ? 1 : k;                                             \
            cm[c] = m; loc[c] = 8 * c + k;                                     \
        }                                                                      \
        float bv = fmaxf(fmaxf(cm[0], cm[1]), fmaxf(cm[2], cm[3]));            \
        const int l0 = (cm[0] == bv) ? loc[0] : INF;                           \
        const int l1 = (cm[1] == bv) ? loc[1] : INF;                           \
        const int l2 = (cm[2] == bv) ? loc[2] : INF;                           \
        const int l3 = (cm[3] == bv) ? loc[3] : INF;                           \
        const int lm = min(min(min(l0, l1), l2), l3);                          \
        int gi = hbase + lm;                                                   \
        const float lv = bv;                                                   \
        bv = fmaxf(bv, __shfl_xor(bv, 1));                                     \
        bv = fmaxf(bv, __shfl_xor(bv, 2));                                     \
        int ii = (lv == bv) ? gi : INF;                                        \
        ii = min(ii, __shfl_xor(ii, 1));                                       \
        ii = min(ii, __shfl_xor(ii, 2));                                       \
        if (lane0) *(float*)(pwr + (WOFF_)) = bv;                              \
        myprev = bv;                                                           \
        bidx_prev = ii;                                                        \
        raw_cur = raw_next_;                                                   \
        __syncthreads();                                                       \
    }

    int t = 1;
    while (t + 1 < L) {
        STEP(t, 0, 512)
        STEP(t + 1, 512, 0)
        t += 2;
    }
    STEP(1023, 0, 512)
#undef STEP

    if (lane0) bprow[(size_t)(NROWS - 1) * T + j] = (u8)bidx_prev;

    float rv = myprev; int rj = j;
#pragma unroll
    for (int m = 4; m <= 32; m <<= 1) {
        const float pv = __shfl_xor(rv, m);
        const int   pj = __shfl_xor(rj, m);
        if (pv > rv || (pv == rv && pj < rj)) { rv = pv; rj = pj; }
    }
    if ((tid & 63) == 0) { swv[tid >> 6] = rv; swj[tid >> 6] = rj; }
    __syncthreads();
    if (tid == 0) {
        float fv = swv[0]; int fj = swj[0];
#pragma unroll
        for (int wv = 1; wv < 8; ++wv) {
            if (swv[wv] > fv || (swv[wv] == fv && swj[wv] < fj)) {
                fv = swv[wv]; fj = swj[wv];
            }
        }
        out[(size_t)B * L + b] = fv;
        out[(size_t)b * L + (L - 1)] = (float)fj;
        lastTag[b] = fj;
    }
}

__global__ __launch_bounds__(T) void segcomp(const u8* __restrict__ bps,
                                             u8* __restrict__ comp)
{
    const int s = blockIdx.x & (NSEG - 1);
    const int b = blockIdx.x >> 4;
    const int r0 = s * SEG;
    const int cnt = (NROWS - r0 < SEG) ? (NROWS - r0) : SEG;

    __shared__ __align__(16) u8 rows[SEG * T];
    const uint4* src = (const uint4*)(bps + ((size_t)b * NROWS + r0) * T);
    uint4* dst = (uint4*)rows;
    const int nvec = cnt * (T / 16);
    for (int k = threadIdx.x; k < nvec; k += T) dst[k] = src[k];
    __syncthreads();

    int x = threadIdx.x;
    for (int k = cnt - 1; k >= 0; --k) x = rows[k * T + x];
    comp[((size_t)b * NSEG + s) * T + threadIdx.x] = (u8)x;
}

__global__ void chainseg(const u8* __restrict__ comp,
                         const int* __restrict__ lastTag,
                         float* __restrict__ out)
{
    const int b = blockIdx.x * blockDim.x + threadIdx.x;
    if (b >= B) return;
    int e = lastTag[b];
#pragma unroll 1
    for (int s = NSEG - 1; s >= 0; --s) {
        e = comp[((size_t)b * NSEG + s) * T + e];
        out[(size_t)b * L + s * SEG] = (float)e;
    }
}

__global__ __launch_bounds__(T) void fillseg(const u8* __restrict__ bps,
                                             const int* __restrict__ lastTag,
                                             float* __restrict__ out)
{
    const int s = blockIdx.x & (NSEG - 1);
    const int b = blockIdx.x >> 4;
    const int r0 = s * SEG;
    const int cnt = (NROWS - r0 < SEG) ? (NROWS - r0) : SEG;

    __shared__ __align__(16) u8 rows[SEG * T];
    const uint4* src = (const uint4*)(bps + ((size_t)b * NROWS + r0) * T);
    uint4* dst = (uint4*)rows;
    const int nvec = cnt * (T / 16);
    for (int k = threadIdx.x; k < nvec; k += T) dst[k] = src[k];
    __syncthreads();

    if (threadIdx.x == 0) {
        int e = (s == NSEG - 1) ? lastTag[b]
                                : (int)out[(size_t)b * L + (size_t)(s + 1) * SEG];
        for (int k = cnt - 1; k >= 1; --k) {
            e = rows[k * T + e];
            out[(size_t)b * L + r0 + k] = (float)e;
        }
    }
}

// ---------------------------------------------------------------------------
extern "C" void kernel_launch(void* const* d_in, const int* in_sizes, int n_in,
                              void* d_out, int out_size, void* d_ws, size_t ws_size,
                              hipStream_t stream)
{
    const float* emit  = (const float*)d_in[0];
    const float* trans = (const float*)d_in[1];
    const float* w     = (const float*)d_in[2];
    float* out = (float*)d_out;

    const size_t prev_bytes = (size_t)B * NROWS * T * sizeof(float); // 268 MB
    const size_t need_fast  = prev_bytes + B * sizeof(int);

    if (ws_size >= need_fast) {
        float* prevws  = (float*)d_ws;
        int*   lastTag = (int*)((char*)d_ws + prev_bytes);
        viterbi_fwd_val<<<B, 512, 0, stream>>>(emit, trans, w, out, prevws, lastTag);
        backtrace<<<B, 64, 0, stream>>>(emit, trans, w, prevws, lastTag, out);
    } else {
        u8*  bps     = (u8*)d_ws;
        u8*  comp    = bps + (size_t)B * NROWS * T;
        int* lastTag = (int*)(comp + (size_t)B * NSEG * T);
        viterbi_fwd_slow<<<B, 512, 0, stream>>>(emit, trans, w, out, bps, lastTag);
        segcomp<<<B * NSEG, T, 0, stream>>>(bps, comp);
        chainseg<<<2, 256, 0, stream>>>(comp, lastTag, out);
        fillseg<<<B * NSEG, T, 0, stream>>>(bps, lastTag, out);
    }
}

// Round 12
// 864.221 us; speedup vs baseline: 2.4588x; 1.0037x over previous
//
#include <hip/hip_runtime.h>

#define B 512
#define L 1024
#define T 128
#define NROWS (L - 1)   /* 1023 */
#define SEG 64
#define NSEG 16

typedef unsigned char u8;
typedef float f2 __attribute__((ext_vector_type(2)));

#define M3(a, b, c) fmaxf(fmaxf((a), (b)), (c))

// Packed fp32 add (VOP3P). Elementwise IEEE f32 add — bitwise identical to
// two v_add_f32.
static __device__ __forceinline__ f2 pkadd(f2 a, f2 b) {
    f2 d;
    asm("v_pk_add_f32 %0, %1, %2" : "=v"(d) : "v"(a), "v"(b));
    return d;
}
// 3-input max (VOP3). Pure selection — bitwise-safe for finite values.
static __device__ __forceinline__ float mx3(float a, float b, float c) {
    float d;
    asm("v_max3_f32 %0, %1, %2, %3" : "=v"(d) : "v"(a), "v"(b), "v"(c));
    return d;
}

// barrier WITHOUT vmcnt(0) drain: LDS visibility only (m201-verified pattern).
#define BAR()                                                  \
    do {                                                       \
        asm volatile("s_waitcnt lgkmcnt(0)" ::: "memory");     \
        __builtin_amdgcn_s_barrier();                          \
        asm volatile("" ::: "memory");                         \
    } while (0)

// ===========================================================================
// FAST PATH (needs ~268 MB workspace)
// ===========================================================================

// ---------------------------------------------------------------------------
// Forward, VALUES ONLY. 256 thr: h = tid&3 owns 32 i's; thread owns TWO
// columns j and j+64 (j = tid>>2 in [0,64)). The 8 LDS granule reads per
// thread are SHARED by both columns -> DS insts/CU/step halve vs R6; the
// per-thread addressing/loop overhead amortizes over 2 columns.
// Exact: s = (prev[i] + obs[j]) + trans[i][j]; max = selection (order-free,
// bitwise — max is associative/idempotent), so prevws stays bitwise R6-equal.
// prevbuf XOR-swizzle (phys g = g ^ (g>>3)) proven in R6/R11.
// ---------------------------------------------------------------------------
__global__ __launch_bounds__(256, 2) void viterbi_fwd_val(
    const float* __restrict__ emit, const float* __restrict__ trans,
    const float* __restrict__ w, float* __restrict__ out,
    float* __restrict__ prevws, int* __restrict__ lastTag)
{
    const int b   = blockIdx.x;
    const int tid = threadIdx.x;
    const int h   = tid & 3;
    const int j   = tid >> 2;           // first column; second is j+64
    const int hbase = h << 5;
    const bool lane0 = (h == 0);

    __shared__ __align__(16) float prevbuf[2 * T];
    __shared__ float swv[4];
    __shared__ int   swj[4];

    // trans for rows [32h,32h+32) x columns {j, j+64}
    f2 tca[16], tcb[16];
#pragma unroll
    for (int q = 0; q < 8; ++q) {
        f2 a, c;
        a.x = trans[(size_t)(hbase + 4 * q + 0) * T + j];
        a.y = trans[(size_t)(hbase + 4 * q + 1) * T + j];
        c.x = trans[(size_t)(hbase + 4 * q + 2) * T + j];
        c.y = trans[(size_t)(hbase + 4 * q + 3) * T + j];
        tca[2 * q] = a; tca[2 * q + 1] = c;
    }
#pragma unroll
    for (int q = 0; q < 8; ++q) {
        f2 a, c;
        a.x = trans[(size_t)(hbase + 4 * q + 0) * T + j + 64];
        a.y = trans[(size_t)(hbase + 4 * q + 1) * T + j + 64];
        c.x = trans[(size_t)(hbase + 4 * q + 2) * T + j + 64];
        c.y = trans[(size_t)(hbase + 4 * q + 3) * T + j + 64];
        tcb[2 * q] = a; tcb[2 * q + 1] = c;
    }

    const float w0 = w[j], w1 = w[j + 64];
    const size_t ebase = (size_t)b * L * T;
    float* prow = prevws + (size_t)b * NROWS * T;

    const char* prd = (const char*)prevbuf + 128 * h;
    // swizzled write byte offsets for both columns (same mapping as R6)
    const int wo0 = 16 * ((j >> 2) ^ (j >> 5)) + 4 * (j & 3);
    const int jj = j + 64;
    const int wo1 = 16 * ((jj >> 2) ^ (jj >> 5)) + 4 * (jj & 3);
    char* pw0 = (char*)prevbuf + wo0;
    char* pw1 = (char*)prevbuf + wo1;

    const float e0a = emit[ebase + j] * w0;
    const float e0b = emit[ebase + jj] * w1;
    if (lane0) { *(float*)pw0 = e0a; *(float*)pw1 = e0b; }
    if (h == 1) { prow[j] = e0a; prow[jj] = e0b; }          // prev row 0
    float mA = e0a, mB = e0b;
    float rc0 = emit[ebase + (size_t)T + j];                // emit row 1
    float rc1 = emit[ebase + (size_t)T + jj];
    float r10 = emit[ebase + (size_t)2 * T + j];            // emit row 2
    float r11 = emit[ebase + (size_t)2 * T + jj];
    float bpA = 0.0f, bpB = 0.0f;
    BAR();

#define SVX(K_) ((K_ & 1) ? sv[(K_) >> 1].y : sv[(K_) >> 1].x)
// one column: 16 pkadd + R6 max tree over the shared granules p0..p7
#define COLMAX(TC_, OD_, BV_)                                                  \
    float BV_;                                                                 \
    {                                                                          \
        f2 sv[16];                                                             \
        sv[0]  = pkadd(pkadd(g0, OD_), TC_[0]);                                \
        sv[1]  = pkadd(pkadd(g1, OD_), TC_[1]);                                \
        sv[2]  = pkadd(pkadd(g2, OD_), TC_[2]);                                \
        sv[3]  = pkadd(pkadd(g3, OD_), TC_[3]);                                \
        sv[4]  = pkadd(pkadd(g4, OD_), TC_[4]);                                \
        sv[5]  = pkadd(pkadd(g5, OD_), TC_[5]);                                \
        sv[6]  = pkadd(pkadd(g6, OD_), TC_[6]);                                \
        sv[7]  = pkadd(pkadd(g7, OD_), TC_[7]);                                \
        sv[8]  = pkadd(pkadd(g8, OD_), TC_[8]);                                \
        sv[9]  = pkadd(pkadd(g9, OD_), TC_[9]);                                \
        sv[10] = pkadd(pkadd(g10, OD_), TC_[10]);                              \
        sv[11] = pkadd(pkadd(g11, OD_), TC_[11]);                              \
        sv[12] = pkadd(pkadd(g12, OD_), TC_[12]);                              \
        sv[13] = pkadd(pkadd(g13, OD_), TC_[13]);                              \
        sv[14] = pkadd(pkadd(g14, OD_), TC_[14]);                              \
        sv[15] = pkadd(pkadd(g15, OD_), TC_[15]);                              \
        const float m0 = mx3(SVX(0),  SVX(1),  SVX(2));                        \
        const float m1 = mx3(SVX(3),  SVX(4),  SVX(5));                        \
        const float m2 = mx3(SVX(6),  SVX(7),  SVX(8));                        \
        const float m3 = mx3(SVX(9),  SVX(10), SVX(11));                       \
        const float m4 = mx3(SVX(12), SVX(13), SVX(14));                       \
        const float m5 = mx3(SVX(15), SVX(16), SVX(17));                       \
        const float m6 = mx3(SVX(18), SVX(19), SVX(20));                       \
        const float m7 = mx3(SVX(21), SVX(22), SVX(23));                       \
        const float m8 = mx3(SVX(24), SVX(25), SVX(26));                       \
        const float m9 = mx3(SVX(27), SVX(28), SVX(29));                       \
        const float m10 = fmaxf(SVX(30), SVX(31));                             \
        const float n0 = mx3(m0, m1, m2);                                      \
        const float n1 = mx3(m3, m4, m5);                                      \
        const float n2 = mx3(m6, m7, m8);                                      \
        const float n3 = fmaxf(m9, m10);                                       \
        BV_ = fmaxf(mx3(n0, n1, n2), n3);                                      \
    }

#define STEP(T_, ROFF_, WOFF_)                                                 \
    {                                                                          \
        const int t_ = (T_);                                                   \
        if (h == 1 && t_ >= 2) {                                               \
            prow[(size_t)(t_ - 1) * T + j]  = bpA;                             \
            prow[(size_t)(t_ - 1) * T + jj] = bpB;                             \
        }                                                                      \
        const int tn_ = (t_ + 2 < L) ? (t_ + 2) : (L - 1);                     \
        const float r20 = emit[ebase + (size_t)tn_ * T + j];                   \
        const float r21 = emit[ebase + (size_t)tn_ * T + jj];                  \
        const float4 p0 = *(const float4*)(prd + (ROFF_) + 16 * (0 ^ h));      \
        const float4 p1 = *(const float4*)(prd + (ROFF_) + 16 * (1 ^ h));      \
        const float4 p2 = *(const float4*)(prd + (ROFF_) + 16 * (2 ^ h));      \
        const float4 p3 = *(const float4*)(prd + (ROFF_) + 16 * (3 ^ h));      \
        const float4 p4 = *(const float4*)(prd + (ROFF_) + 16 * (4 ^ h));      \
        const float4 p5 = *(const float4*)(prd + (ROFF_) + 16 * (5 ^ h));      \
        const float4 p6 = *(const float4*)(prd + (ROFF_) + 16 * (6 ^ h));      \
        const float4 p7 = *(const float4*)(prd + (ROFF_) + 16 * (7 ^ h));      \
        f2 g0;  g0.x  = p0.x; g0.y  = p0.y;                                    \
        f2 g1;  g1.x  = p0.z; g1.y  = p0.w;                                    \
        f2 g2;  g2.x  = p1.x; g2.y  = p1.y;                                    \
        f2 g3;  g3.x  = p1.z; g3.y  = p1.w;                                    \
        f2 g4;  g4.x  = p2.x; g4.y  = p2.y;                                    \
        f2 g5;  g5.x  = p2.z; g5.y  = p2.w;                                    \
        f2 g6;  g6.x  = p3.x; g6.y  = p3.y;                                    \
        f2 g7;  g7.x  = p3.z; g7.y  = p3.w;                                    \
        f2 g8;  g8.x  = p4.x; g8.y  = p4.y;                                    \
        f2 g9;  g9.x  = p4.z; g9.y  = p4.w;                                    \
        f2 g10; g10.x = p5.x; g10.y = p5.y;                                    \
        f2 g11; g11.x = p5.z; g11.y = p5.w;                                    \
        f2 g12; g12.x = p6.x; g12.y = p6.y;                                    \
        f2 g13; g13.x = p6.z; g13.y = p6.w;                                    \
        f2 g14; g14.x = p7.x; g14.y = p7.y;                                    \
        f2 g15; g15.x = p7.z; g15.y = p7.w;                                    \
        const float obs0 = rc0 * w0, obs1 = rc1 * w1;                          \
        f2 od0; od0.x = obs0; od0.y = obs0;                                    \
        f2 od1; od1.x = obs1; od1.y = obs1;                                    \
        COLMAX(tca, od0, bvA0)                                                 \
        COLMAX(tcb, od1, bvB0)                                                 \
        float bvA = bvA0, bvB = bvB0;                                          \
        bvA = fmaxf(bvA, __shfl_xor(bvA, 1));                                  \
        bvB = fmaxf(bvB, __shfl_xor(bvB, 1));                                  \
        bvA = fmaxf(bvA, __shfl_xor(bvA, 2));                                  \
        bvB = fmaxf(bvB, __shfl_xor(bvB, 2));                                  \
        if (lane0) {                                                           \
            *(float*)(pw0 + (WOFF_)) = bvA;                                    \
            *(float*)(pw1 + (WOFF_)) = bvB;                                    \
        }                                                                      \
        mA = bvA; mB = bvB;                                                    \
        bpA = bvA; bpB = bvB;                                                  \
        rc0 = r10; r10 = r20;                                                  \
        rc1 = r11; r11 = r21;                                                  \
        BAR();                                                                 \
    }

    int t = 1;
    while (t + 1 < L) {
        STEP(t, 0, 512)
        STEP(t + 1, 512, 0)
        t += 2;
    }
    STEP(1023, 0, 512)
#undef STEP
#undef COLMAX
#undef SVX

    // final reduce: combine this thread's 2 columns (j < j+64: strict > keeps
    // first-occurrence), butterfly over j bits (4,8,16,32), then 4 wave
    // leaders in ascending wave order (= ascending j).
    float rv; int rj;
    if (mB > mA) { rv = mB; rj = jj; } else { rv = mA; rj = j; }
#pragma unroll
    for (int m = 4; m <= 32; m <<= 1) {
        const float pv = __shfl_xor(rv, m);
        const int   pj = __shfl_xor(rj, m);
        if (pv > rv || (pv == rv && pj < rj)) { rv = pv; rj = pj; }
    }
    if ((tid & 63) == 0) { swv[tid >> 6] = rv; swj[tid >> 6] = rj; }
    __syncthreads();
    if (tid == 0) {
        float fv = swv[0]; int fj = swj[0];
#pragma unroll
        for (int wv = 1; wv < 4; ++wv) {
            if (swv[wv] > fv || (swv[wv] == fv && swj[wv] < fj)) {
                fv = swv[wv]; fj = swj[wv];
            }
        }
        out[(size_t)B * L + b] = fv;
        out[(size_t)b * L + (L - 1)] = (float)fj;
        lastTag[b] = fj;
    }
}

// ---------------------------------------------------------------------------
// Backtrace: ballot-rescan, 8-deep register ring (R5-proven ~117 µs),
// with benign ctz fallback (R10-proven): a miss keeps idx instead of UB.
// ---------------------------------------------------------------------------
__global__ __launch_bounds__(64, 1) void backtrace(
    const float* __restrict__ emit, const float* __restrict__ trans,
    const float* __restrict__ w, const float* __restrict__ prevws,
    const int* __restrict__ lastTag, float* __restrict__ out)
{
    const int b = blockIdx.x;
    const int lane = threadIdx.x;
    __shared__ float transT[T * T];   // 64 KB

    // stage transposed + swizzled: transT[j][i ^ (j&31)] = trans[i][j]
#pragma unroll 4
    for (int it = 0; it < (T * T) / 64; ++it) {
        const int k = it * 64 + lane;
        const int i = k >> 7, jj = k & 127;
        transT[jj * T + (i ^ (jj & 31))] = trans[k];
    }

    const float w0 = w[lane], w1 = w[lane + 64];
    const size_t pbase = (size_t)b * NROWS * T;
    const size_t ebase = (size_t)b * L * T;
    const size_t obase = (size_t)b * L;

    float rp0[8], rp1[8], re0[8], re1[8];
#pragma unroll
    for (int k = 0; k < 8; ++k) {
        rp0[k] = prevws[pbase + (size_t)(1022 - k) * T + lane];
        rp1[k] = prevws[pbase + (size_t)(1022 - k) * T + lane + 64];
        re0[k] = emit[ebase + (size_t)(1023 - k) * T + lane];
        re1[k] = emit[ebase + (size_t)(1023 - k) * T + lane + 64];
    }

    int idx = lastTag[b];
    const float bsc = out[(size_t)B * L + b];
    float pp0 = bsc, pp1 = bsc;
    __syncthreads();

    int r = 1022;

#define BODY(U_)                                                               \
    {                                                                          \
        const float c0_ = rp0[U_], c1_ = rp1[U_];                              \
        const float e0_ = re0[U_], e1_ = re1[U_];                              \
        const int pr = (r >= 8) ? (r - 8) : 0;                                 \
        rp0[U_] = prevws[pbase + (size_t)pr * T + lane];                       \
        rp1[U_] = prevws[pbase + (size_t)pr * T + lane + 64];                  \
        re0[U_] = emit[ebase + (size_t)(pr + 1) * T + lane];                   \
        re1[U_] = emit[ebase + (size_t)(pr + 1) * T + lane + 64];              \
        const int sl = idx & 63;                                               \
        const bool lo = idx < 64;                                              \
        const float bv  = __shfl(lo ? pp0 : pp1, sl);                          \
        const float ew0 = e0_ * w0, ew1 = e1_ * w1;                            \
        const float obs = __shfl(lo ? ew0 : ew1, sl);                          \
        const int xc = lane ^ (idx & 31);                                      \
        const float t0 = transT[idx * T + xc];                                 \
        const float t1 = transT[idx * T + 64 + xc];                            \
        const float s0 = (c0_ + obs) + t0;                                     \
        const float s1 = (c1_ + obs) + t1;                                     \
        const unsigned long long m0 = __ballot(s0 == bv);                      \
        const unsigned long long m1 = __ballot(s1 == bv);                      \
        idx = (m0 != 0ULL) ? __builtin_ctzll(m0)                               \
            : ((m1 != 0ULL) ? 64 + __builtin_ctzll(m1) : idx);                 \
        if (lane == 0) out[obase + r] = (float)idx;                            \
        pp0 = c0_; pp1 = c1_;                                                  \
        --r;                                                                   \
    }

#pragma unroll 1
    for (int g = 0; g < 127; ++g) {    // 127 x 8 = 1016 iters: r = 1022 .. 7
        BODY(0) BODY(1) BODY(2) BODY(3) BODY(4) BODY(5) BODY(6) BODY(7)
    }
    BODY(0) BODY(1) BODY(2) BODY(3) BODY(4) BODY(5) BODY(6)
#undef BODY
}

// ===========================================================================
// FALLBACK PATH (R3 kernels, used when ws_size < 268 MB)
// ===========================================================================
__global__ __launch_bounds__(512, 4) void viterbi_fwd_slow(
    const float* __restrict__ emit, const float* __restrict__ trans,
    const float* __restrict__ w, float* __restrict__ out,
    u8* __restrict__ bps, int* __restrict__ lastTag)
{
    const int b   = blockIdx.x;
    const int tid = threadIdx.x;
    const int h   = tid & 3;
    const int j   = tid >> 2;
    const int hbase = h << 5;
    const bool lane0 = (h == 0);
    const int INF = 0x7fffffff;

    __shared__ __align__(16) float prevbuf[2 * T];
    __shared__ float swv[8];
    __shared__ int   swj[8];

    f2 tc2[16];
#pragma unroll
    for (int q = 0; q < 8; ++q) {
        f2 a, c;
        a.x = trans[(size_t)(hbase + 4 * q + 0) * T + j];
        a.y = trans[(size_t)(hbase + 4 * q + 1) * T + j];
        c.x = trans[(size_t)(hbase + 4 * q + 2) * T + j];
        c.y = trans[(size_t)(hbase + 4 * q + 3) * T + j];
        tc2[2 * q] = a; tc2[2 * q + 1] = c;
    }

    const float wj = w[j];
    const size_t ebase = (size_t)b * L * T;
    u8* bprow = bps + (size_t)b * NROWS * T;

    const char* prd = (const char*)prevbuf + 128 * h;
    char* pwr = (char*)prevbuf + 16 * ((j >> 2) ^ (j >> 5)) + 4 * (j & 3);

    const float e0 = emit[ebase + j] * wj;
    if (lane0) *(float*)pwr = e0;
    float myprev = e0;
    float raw_cur = emit[ebase + (size_t)T + j];
    int bidx_prev = 0;
    __syncthreads();

#define STEP(T_, ROFF_, WOFF_)                                                 \
    {                                                                          \
        const int t_ = (T_);                                                   \
        if (lane0 && t_ >= 2)                                                  \
            bprow[(size_t)(t_ - 2) * T + j] = (u8)bidx_prev;                   \
        const int tn_ = (t_ + 1 < L) ? (t_ + 1) : (L - 1);                     \
        const float raw_next_ = emit[ebase + (size_t)tn_ * T + j];             \
        const float obs_ = raw_cur * wj;                                       \
        f2 od_; od_.x = obs_; od_.y = obs_;                                    \
        f2 sv[16];                                                             \
        _Pragma("unroll")                                                      \
        for (int q = 0; q < 8; ++q) {                                          \
            const float4 p = *(const float4*)(prd + (ROFF_) + 16 * (q ^ h));   \
            f2 plo; plo.x = p.x; plo.y = p.y;                                  \
            f2 phi; phi.x = p.z; phi.y = p.w;                                  \
            sv[2 * q]     = (plo + od_) + tc2[2 * q];                          \
            sv[2 * q + 1] = (phi + od_) + tc2[2 * q + 1];                      \
        }                                                                      \
        float cm[4]; int loc[4];                                               \
        _Pragma("unroll")                                                      \
        for (int c = 0; c < 4; ++c) {                                          \
            const float s0 = sv[4 * c + 0].x, s1 = sv[4 * c + 0].y;            \
            const float s2 = sv[4 * c + 1].x, s3 = sv[4 * c + 1].y;            \
            const float s4 = sv[4 * c + 2].x, s5 = sv[4 * c + 2].y;            \
            const float s6 = sv[4 * c + 3].x, s7 = sv[4 * c + 3].y;            \
            const float m = M3(M3(s0, s1, s2), M3(s3, s4, s5),                 \
                               fmaxf(s6, s7));                                 \
            int k = 0;                                                         \
            k = (s7 == m) ? 7 : k; k = (s6 == m) ? 6 : k;                      \
            k = (s5 == m) ? 5 : k; k = (s4 == m) ? 4 : k;                      \
            k = (s3 == m) ? 3 : k; k = (s2 == m) ? 2 : k;                      \
            k = (s1 == m) ? 1 : k;                                             \
            cm[c] = m; loc[c] = 8 * c + k;                                     \
        }                                                                      \
        float bv = fmaxf(fmaxf(cm[0], cm[1]), fmaxf(cm[2], cm[3]));            \
        const int l0 = (cm[0] == bv) ? loc[0] : INF;                           \
        const int l1 = (cm[1] == bv) ? loc[1] : INF;                           \
        const int l2 = (cm[2] == bv) ? loc[2] : INF;                           \
        const int l3 = (cm[3] == bv) ? loc[3] : INF;                           \
        const int lm = min(min(min(l0, l1), l2), l3);                          \
        int gi = hbase + lm;                                                   \
        const float lv = bv;                                                   \
        bv = fmaxf(bv, __shfl_xor(bv, 1));                                     \
        bv = fmaxf(bv, __shfl_xor(bv, 2));                                     \
        int ii = (lv == bv) ? gi : INF;                                        \
        ii = min(ii, __shfl_xor(ii, 1));                                       \
        ii = min(ii, __shfl_xor(ii, 2));                                       \
        if (lane0) *(float*)(pwr + (WOFF_)) = bv;                              \
        myprev = bv;                                                           \
        bidx_prev = ii;                                                        \
        raw_cur = raw_next_;                                                   \
        __syncthreads();                                                       \
    }

    int t = 1;
    while (t + 1 < L) {
        STEP(t, 0, 512)
        STEP(t + 1, 512, 0)
        t += 2;
    }
    STEP(1023, 0, 512)
#undef STEP

    if (lane0) bprow[(size_t)(NROWS - 1) * T + j] = (u8)bidx_prev;

    float rv = myprev; int rj = j;
#pragma unroll
    for (int m = 4; m <= 32; m <<= 1) {
        const float pv = __shfl_xor(rv, m);
        const int   pj = __shfl_xor(rj, m);
        if (pv > rv || (pv == rv && pj < rj)) { rv = pv; rj = pj; }
    }
    if ((tid & 63) == 0) { swv[tid >> 6] = rv; swj[tid >> 6] = rj; }
    __syncthreads();
    if (tid == 0) {
        float fv = swv[0]; int fj = swj[0];
#pragma unroll
        for (int wv = 1; wv < 8; ++wv) {
            if (swv[wv] > fv || (swv[wv] == fv && swj[wv] < fj)) {
                fv = swv[wv]; fj = swj[wv];
            }
        }
        out[(size_t)B * L + b] = fv;
        out[(size_t)b * L + (L - 1)] = (float)fj;
        lastTag[b] = fj;
    }
}

__global__ __launch_bounds__(T) void segcomp(const u8* __restrict__ bps,
                                             u8* __restrict__ comp)
{
    const int s = blockIdx.x & (NSEG - 1);
    const int b = blockIdx.x >> 4;
    const int r0 = s * SEG;
    const int cnt = (NROWS - r0 < SEG) ? (NROWS - r0) : SEG;

    __shared__ __align__(16) u8 rows[SEG * T];
    const uint4* src = (const uint4*)(bps + ((size_t)b * NROWS + r0) * T);
    uint4* dst = (uint4*)rows;
    const int nvec = cnt * (T / 16);
    for (int k = threadIdx.x; k < nvec; k += T) dst[k] = src[k];
    __syncthreads();

    int x = threadIdx.x;
    for (int k = cnt - 1; k >= 0; --k) x = rows[k * T + x];
    comp[((size_t)b * NSEG + s) * T + threadIdx.x] = (u8)x;
}

__global__ void chainseg(const u8* __restrict__ comp,
                         const int* __restrict__ lastTag,
                         float* __restrict__ out)
{
    const int b = blockIdx.x * blockDim.x + threadIdx.x;
    if (b >= B) return;
    int e = lastTag[b];
#pragma unroll 1
    for (int s = NSEG - 1; s >= 0; --s) {
        e = comp[((size_t)b * NSEG + s) * T + e];
        out[(size_t)b * L + s * SEG] = (float)e;
    }
}

__global__ __launch_bounds__(T) void fillseg(const u8* __restrict__ bps,
                                             const int* __restrict__ lastTag,
                                             float* __restrict__ out)
{
    const int s = blockIdx.x & (NSEG - 1);
    const int b = blockIdx.x >> 4;
    const int r0 = s * SEG;
    const int cnt = (NROWS - r0 < SEG) ? (NROWS - r0) : SEG;

    __shared__ __align__(16) u8 rows[SEG * T];
    const uint4* src = (const uint4*)(bps + ((size_t)b * NROWS + r0) * T);
    uint4* dst = (uint4*)rows;
    const int nvec = cnt * (T / 16);
    for (int k = threadIdx.x; k < nvec; k += T) dst[k] = src[k];
    __syncthreads();

    if (threadIdx.x == 0) {
        int e = (s == NSEG - 1) ? lastTag[b]
                                : (int)out[(size_t)b * L + (size_t)(s + 1) * SEG];
        for (int k = cnt - 1; k >= 1; --k) {
            e = rows[k * T + e];
            out[(size_t)b * L + r0 + k] = (float)e;
        }
    }
}

// ---------------------------------------------------------------------------
extern "C" void kernel_launch(void* const* d_in, const int* in_sizes, int n_in,
                              void* d_out, int out_size, void* d_ws, size_t ws_size,
                              hipStream_t stream)
{
    const float* emit  = (const float*)d_in[0];
    const float* trans = (const float*)d_in[1];
    const float* w     = (const float*)d_in[2];
    float* out = (float*)d_out;

    const size_t prev_bytes = (size_t)B * NROWS * T * sizeof(float); // 268 MB
    const size_t need_fast  = prev_bytes + B * sizeof(int);

    if (ws_size >= need_fast) {
        float* prevws  = (float*)d_ws;
        int*   lastTag = (int*)((char*)d_ws + prev_bytes);
        viterbi_fwd_val<<<B, 256, 0, stream>>>(emit, trans, w, out, prevws, lastTag);
        backtrace<<<B, 64, 0, stream>>>(emit, trans, w, prevws, lastTag, out);
    } else {
        u8*  bps     = (u8*)d_ws;
        u8*  comp    = bps + (size_t)B * NROWS * T;
        int* lastTag = (int*)(comp + (size_t)B * NSEG * T);
        viterbi_fwd_slow<<<B, 512, 0, stream>>>(emit, trans, w, out, bps, lastTag);
        segcomp<<<B * NSEG, T, 0, stream>>>(bps, comp);
        chainseg<<<2, 256, 0, stream>>>(comp, lastTag, out);
        fillseg<<<B * NSEG, T, 0, stream>>>(bps, lastTag, out);
    }
}

// Round 13
// 860.910 us; speedup vs baseline: 2.4683x; 1.0038x over previous
//
#include <hip/hip_runtime.h>

#define B 512
#define L 1024
#define T 128
#define NROWS (L - 1)   /* 1023 */
#define SEG 64
#define NSEG 16

typedef unsigned char u8;
typedef float f2 __attribute__((ext_vector_type(2)));

#define M3(a, b, c) fmaxf(fmaxf((a), (b)), (c))

// Packed fp32 add (VOP3P). Elementwise IEEE f32 add — bitwise identical to
// two v_add_f32.
static __device__ __forceinline__ f2 pkadd(f2 a, f2 b) {
    f2 d;
    asm("v_pk_add_f32 %0, %1, %2" : "=v"(d) : "v"(a), "v"(b));
    return d;
}

// quad_perm DPP cross-lane max (R7-proven bitwise-safe):
// xor1 = [1,0,3,2] = 0xB1, xor2 = [2,3,0,1] = 0x4E
#define DPPMAX(v, CTRL)                                                        \
    fmaxf((v), __int_as_float(__builtin_amdgcn_mov_dpp(                        \
                   __float_as_int(v), (CTRL), 0xf, 0xf, true)))

// barrier WITHOUT vmcnt(0) drain: LDS visibility only (m201-verified pattern).
#define BAR()                                                  \
    do {                                                       \
        asm volatile("s_waitcnt lgkmcnt(0)" ::: "memory");     \
        __builtin_amdgcn_s_barrier();                          \
        asm volatile("" ::: "memory");                         \
    } while (0)

// ===========================================================================
// FAST PATH (needs ~268 MB workspace)
// ===========================================================================

// ---------------------------------------------------------------------------
// Forward, VALUES ONLY. R12 structure frozen (256 thr, h=tid&3, 2 cols/thread,
// shared granule reads, XOR-swizzled prevbuf) — codegen diet only:
//   * max tree in plain C (clang fuses fmaxf pairs to v_max3; no asm walls)
//   * cross-h combine via quad_perm DPP max (no ds_bpermute addr calc)
// Exact: s = (prev[i] + obs[j]) + trans[i][j]; max = selection (order-free,
// bitwise) -> prevws bitwise-identical to R6/R11/R12.
// ---------------------------------------------------------------------------
__global__ __launch_bounds__(256, 2) void viterbi_fwd_val(
    const float* __restrict__ emit, const float* __restrict__ trans,
    const float* __restrict__ w, float* __restrict__ out,
    float* __restrict__ prevws, int* __restrict__ lastTag)
{
    const int b   = blockIdx.x;
    const int tid = threadIdx.x;
    const int h   = tid & 3;
    const int j   = tid >> 2;           // first column; second is j+64
    const int hbase = h << 5;
    const bool lane0 = (h == 0);

    __shared__ __align__(16) float prevbuf[2 * T];
    __shared__ float swv[4];
    __shared__ int   swj[4];

    // trans for rows [32h,32h+32) x columns {j, j+64}
    f2 tca[16], tcb[16];
#pragma unroll
    for (int q = 0; q < 8; ++q) {
        f2 a, c;
        a.x = trans[(size_t)(hbase + 4 * q + 0) * T + j];
        a.y = trans[(size_t)(hbase + 4 * q + 1) * T + j];
        c.x = trans[(size_t)(hbase + 4 * q + 2) * T + j];
        c.y = trans[(size_t)(hbase + 4 * q + 3) * T + j];
        tca[2 * q] = a; tca[2 * q + 1] = c;
    }
#pragma unroll
    for (int q = 0; q < 8; ++q) {
        f2 a, c;
        a.x = trans[(size_t)(hbase + 4 * q + 0) * T + j + 64];
        a.y = trans[(size_t)(hbase + 4 * q + 1) * T + j + 64];
        c.x = trans[(size_t)(hbase + 4 * q + 2) * T + j + 64];
        c.y = trans[(size_t)(hbase + 4 * q + 3) * T + j + 64];
        tcb[2 * q] = a; tcb[2 * q + 1] = c;
    }

    const float w0 = w[j], w1 = w[j + 64];
    const size_t ebase = (size_t)b * L * T;
    float* prow = prevws + (size_t)b * NROWS * T;

    const char* prd = (const char*)prevbuf + 128 * h;
    // swizzled write byte offsets for both columns (same mapping as R6)
    const int wo0 = 16 * ((j >> 2) ^ (j >> 5)) + 4 * (j & 3);
    const int jj = j + 64;
    const int wo1 = 16 * ((jj >> 2) ^ (jj >> 5)) + 4 * (jj & 3);
    char* pw0 = (char*)prevbuf + wo0;
    char* pw1 = (char*)prevbuf + wo1;

    const float e0a = emit[ebase + j] * w0;
    const float e0b = emit[ebase + jj] * w1;
    if (lane0) { *(float*)pw0 = e0a; *(float*)pw1 = e0b; }
    if (h == 1) { prow[j] = e0a; prow[jj] = e0b; }          // prev row 0
    float mA = e0a, mB = e0b;
    float rc0 = emit[ebase + (size_t)T + j];                // emit row 1
    float rc1 = emit[ebase + (size_t)T + jj];
    float r10 = emit[ebase + (size_t)2 * T + j];            // emit row 2
    float r11 = emit[ebase + (size_t)2 * T + jj];
    float bpA = 0.0f, bpB = 0.0f;
    BAR();

#define SVX(K_) ((K_ & 1) ? sv[(K_) >> 1].y : sv[(K_) >> 1].x)
// one column: 16 pkadd + plain-C max tree (clang fuses fmaxf -> v_max3_f32)
#define COLMAX(TC_, OD_, BV_)                                                  \
    float BV_;                                                                 \
    {                                                                          \
        f2 sv[16];                                                             \
        sv[0]  = pkadd(pkadd(g0, OD_), TC_[0]);                                \
        sv[1]  = pkadd(pkadd(g1, OD_), TC_[1]);                                \
        sv[2]  = pkadd(pkadd(g2, OD_), TC_[2]);                                \
        sv[3]  = pkadd(pkadd(g3, OD_), TC_[3]);                                \
        sv[4]  = pkadd(pkadd(g4, OD_), TC_[4]);                                \
        sv[5]  = pkadd(pkadd(g5, OD_), TC_[5]);                                \
        sv[6]  = pkadd(pkadd(g6, OD_), TC_[6]);                                \
        sv[7]  = pkadd(pkadd(g7, OD_), TC_[7]);                                \
        sv[8]  = pkadd(pkadd(g8, OD_), TC_[8]);                                \
        sv[9]  = pkadd(pkadd(g9, OD_), TC_[9]);                                \
        sv[10] = pkadd(pkadd(g10, OD_), TC_[10]);                              \
        sv[11] = pkadd(pkadd(g11, OD_), TC_[11]);                              \
        sv[12] = pkadd(pkadd(g12, OD_), TC_[12]);                              \
        sv[13] = pkadd(pkadd(g13, OD_), TC_[13]);                              \
        sv[14] = pkadd(pkadd(g14, OD_), TC_[14]);                              \
        sv[15] = pkadd(pkadd(g15, OD_), TC_[15]);                              \
        const float m0 = M3(SVX(0),  SVX(1),  SVX(2));                         \
        const float m1 = M3(SVX(3),  SVX(4),  SVX(5));                         \
        const float m2 = M3(SVX(6),  SVX(7),  SVX(8));                         \
        const float m3 = M3(SVX(9),  SVX(10), SVX(11));                        \
        const float m4 = M3(SVX(12), SVX(13), SVX(14));                        \
        const float m5 = M3(SVX(15), SVX(16), SVX(17));                        \
        const float m6 = M3(SVX(18), SVX(19), SVX(20));                        \
        const float m7 = M3(SVX(21), SVX(22), SVX(23));                        \
        const float m8 = M3(SVX(24), SVX(25), SVX(26));                        \
        const float m9 = M3(SVX(27), SVX(28), SVX(29));                        \
        const float m10 = fmaxf(SVX(30), SVX(31));                             \
        const float n0 = M3(m0, m1, m2);                                       \
        const float n1 = M3(m3, m4, m5);                                       \
        const float n2 = M3(m6, m7, m8);                                       \
        const float n3 = fmaxf(m9, m10);                                       \
        BV_ = fmaxf(M3(n0, n1, n2), n3);                                       \
    }

#define STEP(T_, ROFF_, WOFF_)                                                 \
    {                                                                          \
        const int t_ = (T_);                                                   \
        if (h == 1 && t_ >= 2) {                                               \
            prow[(size_t)(t_ - 1) * T + j]  = bpA;                             \
            prow[(size_t)(t_ - 1) * T + jj] = bpB;                             \
        }                                                                      \
        const int tn_ = (t_ + 2 < L) ? (t_ + 2) : (L - 1);                     \
        const float r20 = emit[ebase + (size_t)tn_ * T + j];                   \
        const float r21 = emit[ebase + (size_t)tn_ * T + jj];                  \
        const float4 p0 = *(const float4*)(prd + (ROFF_) + 16 * (0 ^ h));      \
        const float4 p1 = *(const float4*)(prd + (ROFF_) + 16 * (1 ^ h));      \
        const float4 p2 = *(const float4*)(prd + (ROFF_) + 16 * (2 ^ h));      \
        const float4 p3 = *(const float4*)(prd + (ROFF_) + 16 * (3 ^ h));      \
        const float4 p4 = *(const float4*)(prd + (ROFF_) + 16 * (4 ^ h));      \
        const float4 p5 = *(const float4*)(prd + (ROFF_) + 16 * (5 ^ h));      \
        const float4 p6 = *(const float4*)(prd + (ROFF_) + 16 * (6 ^ h));      \
        const float4 p7 = *(const float4*)(prd + (ROFF_) + 16 * (7 ^ h));      \
        f2 g0;  g0.x  = p0.x; g0.y  = p0.y;                                    \
        f2 g1;  g1.x  = p0.z; g1.y  = p0.w;                                    \
        f2 g2;  g2.x  = p1.x; g2.y  = p1.y;                                    \
        f2 g3;  g3.x  = p1.z; g3.y  = p1.w;                                    \
        f2 g4;  g4.x  = p2.x; g4.y  = p2.y;                                    \
        f2 g5;  g5.x  = p2.z; g5.y  = p2.w;                                    \
        f2 g6;  g6.x  = p3.x; g6.y  = p3.y;                                    \
        f2 g7;  g7.x  = p3.z; g7.y  = p3.w;                                    \
        f2 g8;  g8.x  = p4.x; g8.y  = p4.y;                                    \
        f2 g9;  g9.x  = p4.z; g9.y  = p4.w;                                    \
        f2 g10; g10.x = p5.x; g10.y = p5.y;                                    \
        f2 g11; g11.x = p5.z; g11.y = p5.w;                                    \
        f2 g12; g12.x = p6.x; g12.y = p6.y;                                    \
        f2 g13; g13.x = p6.z; g13.y = p6.w;                                    \
        f2 g14; g14.x = p7.x; g14.y = p7.y;                                    \
        f2 g15; g15.x = p7.z; g15.y = p7.w;                                    \
        const float obs0 = rc0 * w0, obs1 = rc1 * w1;                          \
        f2 od0; od0.x = obs0; od0.y = obs0;                                    \
        f2 od1; od1.x = obs1; od1.y = obs1;                                    \
        COLMAX(tca, od0, bvA0)                                                 \
        COLMAX(tcb, od1, bvB0)                                                 \
        float bvA = bvA0, bvB = bvB0;                                          \
        bvA = DPPMAX(bvA, 0xB1);  bvB = DPPMAX(bvB, 0xB1);   /* xor 1 */       \
        bvA = DPPMAX(bvA, 0x4E);  bvB = DPPMAX(bvB, 0x4E);   /* xor 2 */       \
        if (lane0) {                                                           \
            *(float*)(pw0 + (WOFF_)) = bvA;                                    \
            *(float*)(pw1 + (WOFF_)) = bvB;                                    \
        }                                                                      \
        mA = bvA; mB = bvB;                                                    \
        bpA = bvA; bpB = bvB;                                                  \
        rc0 = r10; r10 = r20;                                                  \
        rc1 = r11; r11 = r21;                                                  \
        BAR();                                                                 \
    }

    int t = 1;
    while (t + 1 < L) {
        STEP(t, 0, 512)
        STEP(t + 1, 512, 0)
        t += 2;
    }
    STEP(1023, 0, 512)
#undef STEP
#undef COLMAX
#undef SVX

    // final reduce: combine this thread's 2 columns (j < j+64: strict > keeps
    // first-occurrence), butterfly over j bits (4,8,16,32), then 4 wave
    // leaders in ascending wave order (= ascending j).
    float rv; int rj;
    if (mB > mA) { rv = mB; rj = jj; } else { rv = mA; rj = j; }
#pragma unroll
    for (int m = 4; m <= 32; m <<= 1) {
        const float pv = __shfl_xor(rv, m);
        const int   pj = __shfl_xor(rj, m);
        if (pv > rv || (pv == rv && pj < rj)) { rv = pv; rj = pj; }
    }
    if ((tid & 63) == 0) { swv[tid >> 6] = rv; swj[tid >> 6] = rj; }
    __syncthreads();
    if (tid == 0) {
        float fv = swv[0]; int fj = swj[0];
#pragma unroll
        for (int wv = 1; wv < 4; ++wv) {
            if (swv[wv] > fv || (swv[wv] == fv && swj[wv] < fj)) {
                fv = swv[wv]; fj = swj[wv];
            }
        }
        out[(size_t)B * L + b] = fv;
        out[(size_t)b * L + (L - 1)] = (float)fj;
        lastTag[b] = fj;
    }
}

// ---------------------------------------------------------------------------
// Backtrace: ballot-rescan, 8-deep register ring (R5-proven ~117 µs),
// with benign ctz fallback (R10-proven): a miss keeps idx instead of UB.
// ---------------------------------------------------------------------------
__global__ __launch_bounds__(64, 1) void backtrace(
    const float* __restrict__ emit, const float* __restrict__ trans,
    const float* __restrict__ w, const float* __restrict__ prevws,
    const int* __restrict__ lastTag, float* __restrict__ out)
{
    const int b = blockIdx.x;
    const int lane = threadIdx.x;
    __shared__ float transT[T * T];   // 64 KB

    // stage transposed + swizzled: transT[j][i ^ (j&31)] = trans[i][j]
#pragma unroll 4
    for (int it = 0; it < (T * T) / 64; ++it) {
        const int k = it * 64 + lane;
        const int i = k >> 7, jj = k & 127;
        transT[jj * T + (i ^ (jj & 31))] = trans[k];
    }

    const float w0 = w[lane], w1 = w[lane + 64];
    const size_t pbase = (size_t)b * NROWS * T;
    const size_t ebase = (size_t)b * L * T;
    const size_t obase = (size_t)b * L;

    float rp0[8], rp1[8], re0[8], re1[8];
#pragma unroll
    for (int k = 0; k < 8; ++k) {
        rp0[k] = prevws[pbase + (size_t)(1022 - k) * T + lane];
        rp1[k] = prevws[pbase + (size_t)(1022 - k) * T + lane + 64];
        re0[k] = emit[ebase + (size_t)(1023 - k) * T + lane];
        re1[k] = emit[ebase + (size_t)(1023 - k) * T + lane + 64];
    }

    int idx = lastTag[b];
    const float bsc = out[(size_t)B * L + b];
    float pp0 = bsc, pp1 = bsc;
    __syncthreads();

    int r = 1022;

#define BODY(U_)                                                               \
    {                                                                          \
        const float c0_ = rp0[U_], c1_ = rp1[U_];                              \
        const float e0_ = re0[U_], e1_ = re1[U_];                              \
        const int pr = (r >= 8) ? (r - 8) : 0;                                 \
        rp0[U_] = prevws[pbase + (size_t)pr * T + lane];                       \
        rp1[U_] = prevws[pbase + (size_t)pr * T + lane + 64];                  \
        re0[U_] = emit[ebase + (size_t)(pr + 1) * T + lane];                   \
        re1[U_] = emit[ebase + (size_t)(pr + 1) * T + lane + 64];              \
        const int sl = idx & 63;                                               \
        const bool lo = idx < 64;                                              \
        const float bv  = __shfl(lo ? pp0 : pp1, sl);                          \
        const float ew0 = e0_ * w0, ew1 = e1_ * w1;                            \
        const float obs = __shfl(lo ? ew0 : ew1, sl);                          \
        const int xc = lane ^ (idx & 31);                                      \
        const float t0 = transT[idx * T + xc];                                 \
        const float t1 = transT[idx * T + 64 + xc];                            \
        const float s0 = (c0_ + obs) + t0;                                     \
        const float s1 = (c1_ + obs) + t1;                                     \
        const unsigned long long m0 = __ballot(s0 == bv);                      \
        const unsigned long long m1 = __ballot(s1 == bv);                      \
        idx = (m0 != 0ULL) ? __builtin_ctzll(m0)                               \
            : ((m1 != 0ULL) ? 64 + __builtin_ctzll(m1) : idx);                 \
        if (lane == 0) out[obase + r] = (float)idx;                            \
        pp0 = c0_; pp1 = c1_;                                                  \
        --r;                                                                   \
    }

#pragma unroll 1
    for (int g = 0; g < 127; ++g) {    // 127 x 8 = 1016 iters: r = 1022 .. 7
        BODY(0) BODY(1) BODY(2) BODY(3) BODY(4) BODY(5) BODY(6) BODY(7)
    }
    BODY(0) BODY(1) BODY(2) BODY(3) BODY(4) BODY(5) BODY(6)
#undef BODY
}

// ===========================================================================
// FALLBACK PATH (R3 kernels, used when ws_size < 268 MB)
// ===========================================================================
__global__ __launch_bounds__(512, 4) void viterbi_fwd_slow(
    const float* __restrict__ emit, const float* __restrict__ trans,
    const float* __restrict__ w, float* __restrict__ out,
    u8* __restrict__ bps, int* __restrict__ lastTag)
{
    const int b   = blockIdx.x;
    const int tid = threadIdx.x;
    const int h   = tid & 3;
    const int j   = tid >> 2;
    const int hbase = h << 5;
    const bool lane0 = (h == 0);
    const int INF = 0x7fffffff;

    __shared__ __align__(16) float prevbuf[2 * T];
    __shared__ float swv[8];
    __shared__ int   swj[8];

    f2 tc2[16];
#pragma unroll
    for (int q = 0; q < 8; ++q) {
        f2 a, c;
        a.x = trans[(size_t)(hbase + 4 * q + 0) * T + j];
        a.y = trans[(size_t)(hbase + 4 * q + 1) * T + j];
        c.x = trans[(size_t)(hbase + 4 * q + 2) * T + j];
        c.y = trans[(size_t)(hbase + 4 * q + 3) * T + j];
        tc2[2 * q] = a; tc2[2 * q + 1] = c;
    }

    const float wj = w[j];
    const size_t ebase = (size_t)b * L * T;
    u8* bprow = bps + (size_t)b * NROWS * T;

    const char* prd = (const char*)prevbuf + 128 * h;
    char* pwr = (char*)prevbuf + 16 * ((j >> 2) ^ (j >> 5)) + 4 * (j & 3);

    const float e0 = emit[ebase + j] * wj;
    if (lane0) *(float*)pwr = e0;
    float myprev = e0;
    float raw_cur = emit[ebase + (size_t)T + j];
    int bidx_prev = 0;
    __syncthreads();

#define STEP(T_, ROFF_, WOFF_)                                                 \
    {                                                                          \
        const int t_ = (T_);                                                   \
        if (lane0 && t_ >= 2)                                                  \
            bprow[(size_t)(t_ - 2) * T + j] = (u8)bidx_prev;                   \
        const int tn_ = (t_ + 1 < L) ? (t_ + 1) : (L - 1);                     \
        const float raw_next_ = emit[ebase + (size_t)tn_ * T + j];             \
        const float obs_ = raw_cur * wj;                                       \
        f2 od_; od_.x = obs_; od_.y = obs_;                                    \
        f2 sv[16];                                                             \
        _Pragma("unroll")                                                      \
        for (int q = 0; q < 8; ++q) {                                          \
            const float4 p = *(const float4*)(prd + (ROFF_) + 16 * (q ^ h));   \
            f2 plo; plo.x = p.x; plo.y = p.y;                                  \
            f2 phi; phi.x = p.z; phi.y = p.w;                                  \
            sv[2 * q]     = (plo + od_) + tc2[2 * q];                          \
            sv[2 * q + 1] = (phi + od_) + tc2[2 * q + 1];                      \
        }                                                                      \
        float cm[4]; int loc[4];                                               \
        _Pragma("unroll")                                                      \
        for (int c = 0; c < 4; ++c) {                                          \
            const float s0 = sv[4 * c + 0].x, s1 = sv[4 * c + 0].y;            \
            const float s2 = sv[4 * c + 1].x, s3 = sv[4 * c + 1].y;            \
            const float s4 = sv[4 * c + 2].x, s5 = sv[4 * c + 2].y;            \
            const float s6 = sv[4 * c + 3].x, s7 = sv[4 * c + 3].y;            \
            const float m = M3(M3(s0, s1, s2), M3(s3, s4, s5),                 \
                               fmaxf(s6, s7));                                 \
            int k = 0;                                                         \
            k = (s7 == m) ? 7 : k; k = (s6 == m) ? 6 : k;                      \
            k = (s5 == m) ? 5 : k; k = (s4 == m) ? 4 : k;                      \
            k = (s3 == m) ? 3 : k; k = (s2 == m) ? 2 : k;                      \
            k = (s1 == m) ? 1 : k;                                             \
            cm[c] = m; loc[c] = 8 * c + k;                                     \
        }                                                                      \
        float bv = fmaxf(fmaxf(cm[0], cm[1]), fmaxf(cm[2], cm[3]));            \
        const int l0 = (cm[0] == bv) ? loc[0] : INF;                           \
        const int l1 = (cm[1] == bv) ? loc[1] : INF;                           \
        const int l2 = (cm[2] == bv) ? loc[2] : INF;                           \
        const int l3 = (cm[3] == bv) ? loc[3] : INF;                           \
        const int lm = min(min(min(l0, l1), l2), l3);                          \
        int gi = hbase + lm;                                                   \
        const float lv = bv;                                                   \
        bv = fmaxf(bv, __shfl_xor(bv, 1));                                     \
        bv = fmaxf(bv, __shfl_xor(bv, 2));                                     \
        int ii = (lv == bv) ? gi : INF;                                        \
        ii = min(ii, __shfl_xor(ii, 1));                                       \
        ii = min(ii, __shfl_xor(ii, 2));                                       \
        if (lane0) *(float*)(pwr + (WOFF_)) = bv;                              \
        myprev = bv;                                                           \
        bidx_prev = ii;                                                        \
        raw_cur = raw_next_;                                                   \
        __syncthreads();                                                       \
    }

    int t = 1;
    while (t + 1 < L) {
        STEP(t, 0, 512)
        STEP(t + 1, 512, 0)
        t += 2;
    }
    STEP(1023, 0, 512)
#undef STEP

    if (lane0) bprow[(size_t)(NROWS - 1) * T + j] = (u8)bidx_prev;

    float rv = myprev; int rj = j;
#pragma unroll
    for (int m = 4; m <= 32; m <<= 1) {
        const float pv = __shfl_xor(rv, m);
        const int   pj = __shfl_xor(rj, m);
        if (pv > rv || (pv == rv && pj < rj)) { rv = pv; rj = pj; }
    }
    if ((tid & 63) == 0) { swv[tid >> 6] = rv; swj[tid >> 6] = rj; }
    __syncthreads();
    if (tid == 0) {
        float fv = swv[0]; int fj = swj[0];
#pragma unroll
        for (int wv = 1; wv < 8; ++wv) {
            if (swv[wv] > fv || (swv[wv] == fv && swj[wv] < fj)) {
                fv = swv[wv]; fj = swj[wv];
            }
        }
        out[(size_t)B * L + b] = fv;
        out[(size_t)b * L + (L - 1)] = (float)fj;
        lastTag[b] = fj;
    }
}

__global__ __launch_bounds__(T) void segcomp(const u8* __restrict__ bps,
                                             u8* __restrict__ comp)
{
    const int s = blockIdx.x & (NSEG - 1);
    const int b = blockIdx.x >> 4;
    const int r0 = s * SEG;
    const int cnt = (NROWS - r0 < SEG) ? (NROWS - r0) : SEG;

    __shared__ __align__(16) u8 rows[SEG * T];
    const uint4* src = (const uint4*)(bps + ((size_t)b * NROWS + r0) * T);
    uint4* dst = (uint4*)rows;
    const int nvec = cnt * (T / 16);
    for (int k = threadIdx.x; k < nvec; k += T) dst[k] = src[k];
    __syncthreads();

    int x = threadIdx.x;
    for (int k = cnt - 1; k >= 0; --k) x = rows[k * T + x];
    comp[((size_t)b * NSEG + s) * T + threadIdx.x] = (u8)x;
}

__global__ void chainseg(const u8* __restrict__ comp,
                         const int* __restrict__ lastTag,
                         float* __restrict__ out)
{
    const int b = blockIdx.x * blockDim.x + threadIdx.x;
    if (b >= B) return;
    int e = lastTag[b];
#pragma unroll 1
    for (int s = NSEG - 1; s >= 0; --s) {
        e = comp[((size_t)b * NSEG + s) * T + e];
        out[(size_t)b * L + s * SEG] = (float)e;
    }
}

__global__ __launch_bounds__(T) void fillseg(const u8* __restrict__ bps,
                                             const int* __restrict__ lastTag,
                                             float* __restrict__ out)
{
    const int s = blockIdx.x & (NSEG - 1);
    const int b = blockIdx.x >> 4;
    const int r0 = s * SEG;
    const int cnt = (NROWS - r0 < SEG) ? (NROWS - r0) : SEG;

    __shared__ __align__(16) u8 rows[SEG * T];
    const uint4* src = (const uint4*)(bps + ((size_t)b * NROWS + r0) * T);
    uint4* dst = (uint4*)rows;
    const int nvec = cnt * (T / 16);
    for (int k = threadIdx.x; k < nvec; k += T) dst[k] = src[k];
    __syncthreads();

    if (threadIdx.x == 0) {
        int e = (s == NSEG - 1) ? lastTag[b]
                                : (int)out[(size_t)b * L + (size_t)(s + 1) * SEG];
        for (int k = cnt - 1; k >= 1; --k) {
            e = rows[k * T + e];
            out[(size_t)b * L + r0 + k] = (float)e;
        }
    }
}

// ---------------------------------------------------------------------------
extern "C" void kernel_launch(void* const* d_in, const int* in_sizes, int n_in,
                              void* d_out, int out_size, void* d_ws, size_t ws_size,
                              hipStream_t stream)
{
    const float* emit  = (const float*)d_in[0];
    const float* trans = (const float*)d_in[1];
    const float* w     = (const float*)d_in[2];
    float* out = (float*)d_out;

    const size_t prev_bytes = (size_t)B * NROWS * T * sizeof(float); // 268 MB
    const size_t need_fast  = prev_bytes + B * sizeof(int);

    if (ws_size >= need_fast) {
        float* prevws  = (float*)d_ws;
        int*   lastTag = (int*)((char*)d_ws + prev_bytes);
        viterbi_fwd_val<<<B, 256, 0, stream>>>(emit, trans, w, out, prevws, lastTag);
        backtrace<<<B, 64, 0, stream>>>(emit, trans, w, prevws, lastTag, out);
    } else {
        u8*  bps     = (u8*)d_ws;
        u8*  comp    = bps + (size_t)B * NROWS * T;
        int* lastTag = (int*)(comp + (size_t)B * NSEG * T);
        viterbi_fwd_slow<<<B, 512, 0, stream>>>(emit, trans, w, out, bps, lastTag);
        segcomp<<<B * NSEG, T, 0, stream>>>(bps, comp);
        chainseg<<<2, 256, 0, stream>>>(comp, lastTag, out);
        fillseg<<<B * NSEG, T, 0, stream>>>(bps, lastTag, out);
    }
}